// Round 19
// baseline (6277.104 us; speedup 1.0000x reference)
//
#include <hip/hip_runtime.h>
#include <stdint.h>

#define BB 64
#define TT 512
#define II 512
#define HH 1024
#define OO 512
#define NBLK 256
#define NTHR 512
#define NB 16            // batches per group
#define US 16            // units per slice

// ws float-offsets
#define WS_PK    0                         // h packets: 2 slots x 64b x 512 x 8B = 512 KB
#define WS_ASLAB 131072                    // 64s x 4mt x 48ks x 64ln uint4
#define WS_YSLAB (131072 + 3145728)        // 64s x 32ks x 64ln uint4
#define BTO (BB*TT*OO)
#define BH  (BB*HH)

// LDS: x-acts [64 koct][16] uint4 (16KB) | h-acts (32KB) | ypart [4][64][5] f32
//      | xpart [4][64][4] f32
#define L_HB_U4 1024                       // uint4 index of h region
#define L_YP_F  12288                      // float index of ypart
#define L_XP_F  (12288 + 1280)             // 13568
#define L_BYTES ((13568 + 1024) * 4)       // 58368

typedef __fp16 v8hf __attribute__((ext_vector_type(8)));   // MFMA operand type
typedef float f32x4 __attribute__((ext_vector_type(4)));
typedef _Float16 h2 __attribute__((ext_vector_type(2)));

static __device__ __forceinline__ v8hf bc8(uint4 v) { return __builtin_bit_cast(v8hf, v); }
static __device__ __forceinline__ uint32_t pk_u32(float a, float b) {
  return __builtin_bit_cast(uint32_t, __builtin_amdgcn_cvt_pkrtz(a, b));
}

__device__ __forceinline__ float sigm(float v) { return 1.0f / (1.0f + __expf(-v)); }
__device__ __forceinline__ float tanh_c(float v) {
  v = fminf(fmaxf(v, -20.0f), 20.0f);
  float e = __expf(-2.0f * v);
  return (1.0f - e) / (1.0f + e);
}

// issue-keepalive burn used inside the sentinel spin (no memory traffic)
__device__ __forceinline__ void burn64() {
  float a = 0.0f;
  #pragma unroll
  for (int i = 0; i < 64; ++i)
    asm volatile("v_fmac_f32 %0, %1, %1" : "+v"(a) : "v"(1.00001f));
  asm volatile("" :: "v"(a));
}

// agent-scope (sc0 sc1): per-access coherence, NO cache-wide ops, NO atomics.
// 8B accesses are single-copy atomic -> {h-pair, epoch} packets are consistent.
__device__ __forceinline__ uint2 cohere_ld8(const void* p) {
  unsigned long long q = __hip_atomic_load((const unsigned long long*)p,
                                           __ATOMIC_RELAXED, __HIP_MEMORY_SCOPE_AGENT);
  return __builtin_bit_cast(uint2, q);
}
__device__ __forceinline__ void cohere_st8(void* p, uint32_t lo, uint32_t hi) {
  uint2 v = make_uint2(lo, hi);
  __hip_atomic_store((unsigned long long*)p, __builtin_bit_cast(unsigned long long, v),
                     __ATOMIC_RELAXED, __HIP_MEMORY_SCOPE_AGENT);
}

// -------- prep: pack A-slab (gate weights, MFMA A-frag order) + y-slab --------
__global__ void __launch_bounds__(256) prep(
    const float* __restrict__ Wf, const float* __restrict__ Wi,
    const float* __restrict__ Wc, const float* __restrict__ Wo,
    const float* __restrict__ Wfc, float* __restrict__ ws)
{
  const int NA = 64 * 4 * 48 * 64;
  const int NY = 64 * 32 * 64;
  int idx = blockIdx.x * 256 + threadIdx.x;
  if (idx < NA) {
    int s = idx / (4 * 48 * 64);
    int rem = idx % (4 * 48 * 64);
    int mt = rem / (48 * 64);
    int rem2 = rem % (48 * 64);
    int ks = rem2 >> 6, ln = rem2 & 63;
    int r = ln & 15, kq = ln >> 4;
    int unit = s * 16 + mt * 4 + (r >> 2), gate = r & 3;
    const float* W = (gate == 0) ? Wf : (gate == 1) ? Wi : (gate == 2) ? Wc : Wo;
    const float* src = W + (size_t)unit * 1536 + ks * 32 + kq * 8;
    uint32_t p[4];
    #pragma unroll
    for (int j = 0; j < 4; ++j) {
      h2 t; t.x = (_Float16)src[2*j]; t.y = (_Float16)src[2*j+1];   // RNE
      p[j] = __builtin_bit_cast(uint32_t, t);
    }
    ((uint4*)(ws + WS_ASLAB))[idx] = make_uint4(p[0], p[1], p[2], p[3]);
  } else if (idx < NA + NY) {
    int j2 = idx - NA;
    int s = j2 / (32 * 64);
    int rem = j2 % (32 * 64);
    int ks = rem >> 6, ln = rem & 63;
    int r = ln & 15, kq = ln >> 4;
    uint4 outv = make_uint4(0, 0, 0, 0);
    if (r < 8) {
      const float* src = Wfc + (size_t)(s * 8 + r) * 1024 + ks * 32 + kq * 8;
      uint32_t p[4];
      #pragma unroll
      for (int j = 0; j < 4; ++j) {
        h2 t; t.x = (_Float16)src[2*j]; t.y = (_Float16)src[2*j+1];
        p[j] = __builtin_bit_cast(uint32_t, t);
      }
      outv = make_uint4(p[0], p[1], p[2], p[3]);
    }
    ((uint4*)(ws + WS_YSLAB))[j2] = outv;
  }
}

__global__ void __launch_bounds__(NTHR, 2)
lstm_kernel(const float* __restrict__ x,
            const float* __restrict__ bf, const float* __restrict__ bi,
            const float* __restrict__ bc, const float* __restrict__ bo,
            const float* __restrict__ bfc,
            float* __restrict__ out, float* __restrict__ ws)
{
  extern __shared__ float ldsf[];
  uint4* acts4 = (uint4*)ldsf;               // x: [0,1024) ; h: [1024,3072)
  float* ypart = ldsf + L_YP_F;              // [4][64][5]
  float* xpart = ldsf + L_XP_F;              // [4][64][4]

  const int tid  = threadIdx.x;
  const int blk  = blockIdx.x;
  const int wave = tid >> 6;
  const int lane = tid & 63;
  const bool isGate = (wave < 4);
  const int mt = wave & 3;                   // m-tile for this wave's role
  const int g = blk >> 6, s = blk & 63;
  const int b0 = g * NB;
  const int u0 = s * US;

  uint2* hpk = (uint2*)(ws + WS_PK);         // [2 slots][64 batch][512 unit-pairs]

  const int bq = lane & 15, kq = lane >> 4;  // MFMA B-col/batch ; k-group & row-quad
  const int tid2 = tid & 255;                // aux staging index
  const int sb = tid2 >> 4, sj = tid2 & 15;  // x staging: batch, row/16
  const int gb = tid >> 5, gj = tid & 31;    // gather: batch(16), slice-pair(32)

  // ---- persistent fragments (role-split to fit 2 waves/SIMD) ----
  v8hf Ah[32];                               // gate: h-part A-frags (128 VGPR)
  v8hf Ax[16];                               // aux: x-part A-frags  (64 VGPR)
  v8hf Yw[8];                                // aux: Wfc k-slice     (32 VGPR)
  if (isGate) {
    const uint4* wpA = (const uint4*)(ws + WS_ASLAB)
                     + ((size_t)(s * 4 + mt) * 48 + 16) * 64 + lane;
    #pragma unroll
    for (int k = 0; k < 32; ++k) Ah[k] = bc8(wpA[k * 64]);
  } else {
    const uint4* wpA = (const uint4*)(ws + WS_ASLAB)
                     + ((size_t)(s * 4 + mt) * 48) * 64 + lane;
    #pragma unroll
    for (int k = 0; k < 16; ++k) Ax[k] = bc8(wpA[k * 64]);
    const uint4* wpY = (const uint4*)(ws + WS_YSLAB)
                     + ((size_t)(s * 32 + mt * 8)) * 64 + lane;
    #pragma unroll
    for (int k = 0; k < 8; ++k) Yw[k] = bc8(wpY[k * 64]);
  }
  const int unit = u0 + mt * 4 + kq;         // gate waves: owned unit
  const float bsf = isGate ? bf[unit] : 0.f;
  const float bsi = isGate ? bi[unit] : 0.f;
  const float bsc = isGate ? bc[unit] : 0.f;
  const float bso = isGate ? bo[unit] : 0.f;
  const float ybias = (tid < 128) ? bfc[s * 8 + (tid >> 4)] : 0.0f;
  float cstate = 0.0f;

  // ---- prologue ----
  if (!isGate) {                             // aux: stage x_0
    const float* xs = x + ((size_t)(b0 + sb) * TT + 0) * II + sj * 32;
    #pragma unroll
    for (int v = 0; v < 4; ++v) {
      float4 u = ((const float4*)xs)[2*v], w = ((const float4*)xs)[2*v+1];
      acts4[sj * 64 + v * 16 + (sb ^ (sj & 7))] =
          make_uint4(pk_u32(u.x,u.y), pk_u32(u.z,u.w), pk_u32(w.x,w.y), pk_u32(w.z,w.w));
    }
  } else {                                   // gate: zero h-LDS (h_{-1}=0)
    #pragma unroll
    for (int j = 0; j < 8; ++j)
      acts4[L_HB_U4 + tid2 * 8 + j] = make_uint4(0,0,0,0);
  }
  __syncthreads();
  if (!isGate) {                             // aux: xpart(0)
    f32x4 ac[4];
    #pragma unroll
    for (int j = 0; j < 4; ++j) ac[j] = (f32x4){0.f,0.f,0.f,0.f};
    #pragma unroll
    for (int ks = 0; ks < 16; ++ks) {
      uint4 bv = acts4[ks * 64 + kq * 16 + (bq ^ (ks & 7))];
      ac[ks & 3] = __builtin_amdgcn_mfma_f32_16x16x32_f16(Ax[ks], bc8(bv), ac[ks & 3], 0, 0, 0);
    }
    f32x4 t = (ac[0] + ac[1]) + (ac[2] + ac[3]);
    float* xp = xpart + (mt * 64 + lane) * 4;
    xp[0] = t[0]; xp[1] = t[1]; xp[2] = t[2]; xp[3] = t[3];
  }
  __syncthreads();

  for (int it = 0; it <= TT; ++it) {
    const bool xok = (it + 1 < TT);

    if (isGate) {
      // ---- GATE: C-init from xpart, 32 h-MFMA, state, packet publish ----
      if (it < TT) {
        const float* xp = xpart + (mt * 64 + lane) * 4;
        f32x4 ac[4];
        ac[0] = (f32x4){xp[0], xp[1], xp[2], xp[3]};
        ac[1] = (f32x4){0.f,0.f,0.f,0.f};
        ac[2] = (f32x4){0.f,0.f,0.f,0.f};
        ac[3] = (f32x4){0.f,0.f,0.f,0.f};
        #pragma unroll
        for (int ksh = 0; ksh < 32; ++ksh) {
          uint4 bv = acts4[L_HB_U4 + ksh * 64 + kq * 16 + (bq ^ (ksh & 7))];
          ac[ksh & 3] = __builtin_amdgcn_mfma_f32_16x16x32_f16(Ah[ksh], bc8(bv), ac[ksh & 3], 0, 0, 0);
        }
        f32x4 t = (ac[0] + ac[1]) + (ac[2] + ac[3]);

        float gf = sigm(t[0] + bsf);
        float gi = sigm(t[1] + bsi);
        float gc = tanh_c(t[2] + bsc);
        float go = sigm(t[3] + bso);
        cstate = gf * cstate + gi * gc;
        float hv = go * tanh_c(cstate);

        // ---- PUBLISH: {h-pair, epoch} 8B atomic packets; fire-and-forget,
        //      NO drain, NO flag — each packet is self-validating. ----
        uint32_t hu = (uint32_t)__builtin_bit_cast(unsigned short, (_Float16)hv);
        uint32_t pair = hu | ((uint32_t)__shfl_down((int)hu, 16) << 16);  // (kq,kq+1)
        if ((kq & 1) == 0) {
          size_t pidx = (size_t)((it + 1) & 1) * (BB * 512)
                      + (size_t)(b0 + bq) * 512 + (s * 8 + mt * 2 + (kq >> 1));
          cohere_st8(&hpk[pidx], pair, (uint32_t)(it + 1));
        }
        if (it == TT - 1) {
          out[(size_t)BTO + (size_t)(b0 + bq) * HH + unit] = hv;
          out[(size_t)BTO + BH + (size_t)(b0 + bq) * HH + unit] = cstate;
        }
      }
    } else {
      // ---- AUX: y-MFMA for y_{it-1} over h_{it-1} (still in h-LDS) ----
      if (it > 0) {
        f32x4 yc = (f32x4){0.f,0.f,0.f,0.f};
        #pragma unroll
        for (int k = 0; k < 8; ++k) {
          int ksh = mt * 8 + k;
          uint4 bv = acts4[L_HB_U4 + ksh * 64 + kq * 16 + (bq ^ (ksh & 7))];
          yc = __builtin_amdgcn_mfma_f32_16x16x32_f16(Yw[k], bc8(bv), yc, 0, 0, 0);
        }
        float* yp = ypart + (mt * 64 + lane) * 5;
        yp[0] = yc[0]; yp[1] = yc[1]; yp[2] = yc[2]; yp[3] = yc[3];
      }
    }
    __syncthreads();                         // S1: h-LDS reads done; ypart ready

    // ---- gate threads: y finalize ; aux threads: x write ----
    if (tid < 128 && it > 0) {
      int fb = tid & 15, rr = tid >> 4;
      int l = (rr >> 2) * 16 + fb;
      float yv = ybias;
      #pragma unroll
      for (int w = 0; w < 4; ++w) yv += ypart[(w * 64 + l) * 5 + (rr & 3)];
      out[(size_t)(b0 + fb) * (TT * OO) + (size_t)(it - 1) * OO + s * 8 + rr] = yv;
    }
    if (!isGate && xok) {
      const float* xs = x + ((size_t)(b0 + sb) * TT + (it + 1)) * II + sj * 32;
      float4 xr[8];
      #pragma unroll
      for (int v = 0; v < 8; ++v) xr[v] = ((const float4*)xs)[v];
      #pragma unroll
      for (int v = 0; v < 4; ++v)
        acts4[sj * 64 + v * 16 + (sb ^ (sj & 7))] =
            make_uint4(pk_u32(xr[2*v].x, xr[2*v].y), pk_u32(xr[2*v].z, xr[2*v].w),
                       pk_u32(xr[2*v+1].x, xr[2*v+1].y), pk_u32(xr[2*v+1].z, xr[2*v+1].w));
    }
    __syncthreads();                         // S2: x-LDS ready

    // ---- aux: xpart(it+1) ----
    if (!isGate && xok) {
      f32x4 ac[4];
      #pragma unroll
      for (int j = 0; j < 4; ++j) ac[j] = (f32x4){0.f,0.f,0.f,0.f};
      #pragma unroll
      for (int ks = 0; ks < 16; ++ks) {
        uint4 bv = acts4[ks * 64 + kq * 16 + (bq ^ (ks & 7))];
        ac[ks & 3] = __builtin_amdgcn_mfma_f32_16x16x32_f16(Ax[ks], bc8(bv), ac[ks & 3], 0, 0, 0);
      }
      f32x4 t = (ac[0] + ac[1]) + (ac[2] + ac[3]);
      float* xp = xpart + (mt * 64 + lane) * 4;
      xp[0] = t[0]; xp[1] = t[1]; xp[2] = t[2]; xp[3] = t[3];
    }

    if (it < TT) {
      // ---- CONSUME: sentinel spin (16B/thread/retry) then batched gather
      //      with per-packet epoch validation (rare stragglers retried) ----
      const uint32_t tgt = (uint32_t)(it + 1);
      const uint2* src = hpk + (size_t)((it + 1) & 1) * (BB * 512)
                       + (size_t)(b0 + gb) * 512 + gj * 16;
      for (;;) {
        uint2 sa = cohere_ld8(&src[7]);
        uint2 sb2 = cohere_ld8(&src[15]);
        burn64();                            // overlaps the load round-trip
        if (sa.y == tgt && sb2.y == tgt) break;
      }
      uint2 p[16];
      #pragma unroll
      for (int m = 0; m < 16; ++m) p[m] = cohere_ld8(&src[m]);
      uint32_t w[16];
      #pragma unroll
      for (int m = 0; m < 16; ++m) {
        while (p[m].y != tgt) p[m] = cohere_ld8(&src[m]);
        w[m] = p[m].x;
      }
      #pragma unroll
      for (int sub = 0; sub < 4; ++sub)
        acts4[L_HB_U4 + gj * 64 + sub * 16 + (gb ^ (gj & 7))] =
            make_uint4(w[4*sub], w[4*sub+1], w[4*sub+2], w[4*sub+3]);
      __syncthreads();                       // S3: h + xpart ready for it+1
    }
  }
}

extern "C" void kernel_launch(void* const* d_in, const int* in_sizes, int n_in,
                              void* d_out, int out_size, void* d_ws, size_t ws_size,
                              hipStream_t stream) {
  (void)in_sizes; (void)n_in; (void)out_size; (void)ws_size;
  const float* x   = (const float*)d_in[0];
  const float* Wf  = (const float*)d_in[1];
  const float* bf  = (const float*)d_in[2];
  const float* Wi  = (const float*)d_in[3];
  const float* bi  = (const float*)d_in[4];
  const float* Wc  = (const float*)d_in[5];
  const float* bc  = (const float*)d_in[6];
  const float* Wo  = (const float*)d_in[7];
  const float* bo  = (const float*)d_in[8];
  const float* Wfc = (const float*)d_in[9];
  const float* bfc = (const float*)d_in[10];
  float* out = (float*)d_out;
  float* ws  = (float*)d_ws;

  // zero the packet region each call (epochs reset; replay-safe, in-graph)
  (void)hipMemsetAsync(d_ws, 0, (size_t)2 * BB * 512 * 8, stream);

  // pack fp16 MFMA fragment slabs
  const int nprep = 64 * 4 * 48 * 64 + 64 * 32 * 64;
  prep<<<dim3((nprep + 255) / 256), dim3(256), 0, stream>>>(Wf, Wi, Wc, Wo, Wfc, ws);

  // plain launch; 256 blocks <= 256 CUs => all co-resident for the spin protocol
  lstm_kernel<<<dim3(NBLK), dim3(NTHR), L_BYTES, stream>>>(
      x, bf, bi, bc, bo, bfc, out, ws);
}

// Round 20
// 3511.827 us; speedup vs baseline: 1.7874x; 1.7874x over previous
//
#include <hip/hip_runtime.h>
#include <stdint.h>

#define BB 64
#define TT 512
#define II 512
#define HH 1024
#define OO 512
#define NBLK 256
#define NTHR 512
#define NB 16            // batches per group
#define US 16            // units per slice

// ws float-offsets
#define WS_HBUF  1280                      // flags live in [0,1280): 4 groups x 256 words
#define WS_ASLAB 66816                     // 64s x 4mt x 48ks x 64ln uint4
#define WS_YSLAB 3212544                   // 64s x 32ks x 64ln uint4
#define BTO (BB*TT*OO)
#define BH  (BB*HH)

// LDS: x-acts [64 koct][16] uint4 (16KB) | h-acts (32KB) | ypart [4][64][5] f32
//      | xpart [4][64][4] f32 | barrier counter
#define L_HB_U4 1024                       // uint4 index of h region
#define L_YP_F  12288                      // float index of ypart
#define L_XP_F  (12288 + 1280)             // 13568
#define L_BAR_F (L_XP_F + 1024)            // 14592
#define L_BYTES ((L_BAR_F + 16) * 4)       // 58432

typedef __fp16 v8hf __attribute__((ext_vector_type(8)));   // MFMA operand type
typedef float f32x4 __attribute__((ext_vector_type(4)));
typedef _Float16 h2 __attribute__((ext_vector_type(2)));

static __device__ __forceinline__ v8hf bc8(uint4 v) { return __builtin_bit_cast(v8hf, v); }
static __device__ __forceinline__ uint32_t pk_u32(float a, float b) {
  return __builtin_bit_cast(uint32_t, __builtin_amdgcn_cvt_pkrtz(a, b));
}

__device__ __forceinline__ float sigm(float v) { return 1.0f / (1.0f + __expf(-v)); }
__device__ __forceinline__ float tanh_c(float v) {
  v = fminf(fmaxf(v, -20.0f), 20.0f);
  float e = __expf(-2.0f * v);
  return (1.0f - e) / (1.0f + e);
}

// small register-only FMA burn: keeps the SIMD issuing during spins so DVFS
// sees a busy chip (the r16/r18 kernels sleep ~90% of wall at s_barrier).
__device__ __forceinline__ void burn16() {
  float a = 0.0f;
  #pragma unroll
  for (int i = 0; i < 16; ++i)
    asm volatile("v_fmac_f32 %0, %1, %1" : "+v"(a) : "v"(1.00001f));
  asm volatile("" :: "v"(a));
}

// LDS spin barrier (replaces s_barrier in the hot loop): monotone phase
// counter, relaxed LDS atomics (CU-local, no cache ops), FMA burn while
// waiting. All 8 waves call it the same number of times.
__device__ __forceinline__ void lds_barrier(uint32_t* bar, uint32_t ph, int lane) {
  asm volatile("s_waitcnt lgkmcnt(0)" ::: "memory");
  if (lane == 0)
    (void)__hip_atomic_fetch_add(bar, 1u, __ATOMIC_RELAXED, __HIP_MEMORY_SCOPE_WORKGROUP);
  while (__hip_atomic_load(bar, __ATOMIC_RELAXED, __HIP_MEMORY_SCOPE_WORKGROUP) < 8u * ph)
    burn16();
  __builtin_amdgcn_sched_barrier(0);
  asm volatile("" ::: "memory");
}

// agent-scope (sc0 sc1): per-access coherence, NO cache-wide ops, NO RMW atomics
__device__ __forceinline__ uint2 cohere_ld8(const void* p) {
  unsigned long long q = __hip_atomic_load((const unsigned long long*)p,
                                           __ATOMIC_RELAXED, __HIP_MEMORY_SCOPE_AGENT);
  return __builtin_bit_cast(uint2, q);
}
__device__ __forceinline__ void cohere_st8(void* p, uint32_t lo, uint32_t hi) {
  uint2 v = make_uint2(lo, hi);
  __hip_atomic_store((unsigned long long*)p, __builtin_bit_cast(unsigned long long, v),
                     __ATOMIC_RELAXED, __HIP_MEMORY_SCOPE_AGENT);
}
__device__ __forceinline__ void cohere_st4(void* p, uint32_t v) {
  __hip_atomic_store((uint32_t*)p, v, __ATOMIC_RELAXED, __HIP_MEMORY_SCOPE_AGENT);
}

// -------- prep: pack A-slab (gate weights, MFMA A-frag order) + y-slab --------
__global__ void __launch_bounds__(256) prep(
    const float* __restrict__ Wf, const float* __restrict__ Wi,
    const float* __restrict__ Wc, const float* __restrict__ Wo,
    const float* __restrict__ Wfc, float* __restrict__ ws)
{
  const int NA = 64 * 4 * 48 * 64;
  const int NY = 64 * 32 * 64;
  int idx = blockIdx.x * 256 + threadIdx.x;
  if (idx < NA) {
    int s = idx / (4 * 48 * 64);
    int rem = idx % (4 * 48 * 64);
    int mt = rem / (48 * 64);
    int rem2 = rem % (48 * 64);
    int ks = rem2 >> 6, ln = rem2 & 63;
    int r = ln & 15, kq = ln >> 4;
    int unit = s * 16 + mt * 4 + (r >> 2), gate = r & 3;
    const float* W = (gate == 0) ? Wf : (gate == 1) ? Wi : (gate == 2) ? Wc : Wo;
    const float* src = W + (size_t)unit * 1536 + ks * 32 + kq * 8;
    uint32_t p[4];
    #pragma unroll
    for (int j = 0; j < 4; ++j) {
      h2 t; t.x = (_Float16)src[2*j]; t.y = (_Float16)src[2*j+1];   // RNE
      p[j] = __builtin_bit_cast(uint32_t, t);
    }
    ((uint4*)(ws + WS_ASLAB))[idx] = make_uint4(p[0], p[1], p[2], p[3]);
  } else if (idx < NA + NY) {
    int j2 = idx - NA;
    int s = j2 / (32 * 64);
    int rem = j2 % (32 * 64);
    int ks = rem >> 6, ln = rem & 63;
    int r = ln & 15, kq = ln >> 4;
    uint4 outv = make_uint4(0, 0, 0, 0);
    if (r < 8) {
      const float* src = Wfc + (size_t)(s * 8 + r) * 1024 + ks * 32 + kq * 8;
      uint32_t p[4];
      #pragma unroll
      for (int j = 0; j < 4; ++j) {
        h2 t; t.x = (_Float16)src[2*j]; t.y = (_Float16)src[2*j+1];
        p[j] = __builtin_bit_cast(uint32_t, t);
      }
      outv = make_uint4(p[0], p[1], p[2], p[3]);
    }
    ((uint4*)(ws + WS_YSLAB))[j2] = outv;
  }
}

__global__ void __launch_bounds__(NTHR, 2)
lstm_kernel(const float* __restrict__ x,
            const float* __restrict__ bf, const float* __restrict__ bi,
            const float* __restrict__ bc, const float* __restrict__ bo,
            const float* __restrict__ bfc,
            float* __restrict__ out, float* __restrict__ ws)
{
  extern __shared__ float ldsf[];
  uint4* acts4 = (uint4*)ldsf;               // x: [0,1024) ; h: [1024,3072)
  float* ypart = ldsf + L_YP_F;              // [4][64][5]
  float* xpart = ldsf + L_XP_F;              // [4][64][4]
  uint32_t* bar = (uint32_t*)(ldsf + L_BAR_F);

  const int tid  = threadIdx.x;
  const int blk  = blockIdx.x;
  const int wave = tid >> 6;
  const int lane = tid & 63;
  const bool isGate = (wave < 4);
  const int mt = wave & 3;                   // m-tile for this wave's role
  const int g = blk >> 6, s = blk & 63;
  const int b0 = g * NB;
  const int u0 = s * US;

  uint32_t* ctrl  = (uint32_t*)ws;
  uint32_t* flags = ctrl + g * 256;          // flags[s*4+mt] = it+1 (per gate wave)
  ushort* hb16 = (ushort*)(ws + WS_HBUF);

  const int bq = lane & 15, kq = lane >> 4;  // MFMA B-col/batch ; k-group & row-quad
  const int tid2 = tid & 255;                // aux staging index
  const int sb = tid2 >> 4, sj = tid2 & 15;  // x staging: batch, row/16
  const int gb = tid >> 5, gj = tid & 31;    // gather: batch(16), slice-pair(32)

  // ---- persistent fragments (role-split to fit 2 waves/SIMD) ----
  v8hf Ah[32];                               // gate: h-part A-frags (128 VGPR)
  v8hf Ax[16];                               // aux: x-part A-frags  (64 VGPR)
  v8hf Yw[8];                                // aux: Wfc k-slice     (32 VGPR)
  if (isGate) {
    const uint4* wpA = (const uint4*)(ws + WS_ASLAB)
                     + ((size_t)(s * 4 + mt) * 48 + 16) * 64 + lane;
    #pragma unroll
    for (int k = 0; k < 32; ++k) Ah[k] = bc8(wpA[k * 64]);
  } else {
    const uint4* wpA = (const uint4*)(ws + WS_ASLAB)
                     + ((size_t)(s * 4 + mt) * 48) * 64 + lane;
    #pragma unroll
    for (int k = 0; k < 16; ++k) Ax[k] = bc8(wpA[k * 64]);
    const uint4* wpY = (const uint4*)(ws + WS_YSLAB)
                     + ((size_t)(s * 32 + mt * 8)) * 64 + lane;
    #pragma unroll
    for (int k = 0; k < 8; ++k) Yw[k] = bc8(wpY[k * 64]);
  }
  const int unit = u0 + mt * 4 + kq;         // gate waves: owned unit
  const float bsf = isGate ? bf[unit] : 0.f;
  const float bsi = isGate ? bi[unit] : 0.f;
  const float bsc = isGate ? bc[unit] : 0.f;
  const float bso = isGate ? bo[unit] : 0.f;
  const float ybias = (tid < 128) ? bfc[s * 8 + (tid >> 4)] : 0.0f;
  float cstate = 0.0f;
  uint32_t bphase = 0;                       // LDS-barrier phase (uniform)

  // ---- prologue ----
  if (tid == 0) *bar = 0;
  if (!isGate) {                             // aux: stage x_0
    const float* xs = x + ((size_t)(b0 + sb) * TT + 0) * II + sj * 32;
    #pragma unroll
    for (int v = 0; v < 4; ++v) {
      float4 u = ((const float4*)xs)[2*v], w = ((const float4*)xs)[2*v+1];
      acts4[sj * 64 + v * 16 + (sb ^ (sj & 7))] =
          make_uint4(pk_u32(u.x,u.y), pk_u32(u.z,u.w), pk_u32(w.x,w.y), pk_u32(w.z,w.w));
    }
  } else {                                   // gate: zero h-LDS (h_{-1}=0)
    #pragma unroll
    for (int j = 0; j < 8; ++j)
      acts4[L_HB_U4 + tid2 * 8 + j] = make_uint4(0,0,0,0);
  }
  __syncthreads();
  if (!isGate) {                             // aux: xpart(0)
    f32x4 ac[4];
    #pragma unroll
    for (int j = 0; j < 4; ++j) ac[j] = (f32x4){0.f,0.f,0.f,0.f};
    #pragma unroll
    for (int ks = 0; ks < 16; ++ks) {
      uint4 bv = acts4[ks * 64 + kq * 16 + (bq ^ (ks & 7))];
      ac[ks & 3] = __builtin_amdgcn_mfma_f32_16x16x32_f16(Ax[ks], bc8(bv), ac[ks & 3], 0, 0, 0);
    }
    f32x4 t = (ac[0] + ac[1]) + (ac[2] + ac[3]);
    float* xp = xpart + (mt * 64 + lane) * 4;
    xp[0] = t[0]; xp[1] = t[1]; xp[2] = t[2]; xp[3] = t[3];
  }
  __syncthreads();

  for (int it = 0; it <= TT; ++it) {
    const bool xok = (it + 1 < TT);

    if (isGate) {
      // ---- GATE: C-init from xpart, 32 h-MFMA, state, h-store, OWN flag ----
      if (it < TT) {
        const float* xp = xpart + (mt * 64 + lane) * 4;
        f32x4 ac[4];
        ac[0] = (f32x4){xp[0], xp[1], xp[2], xp[3]};
        ac[1] = (f32x4){0.f,0.f,0.f,0.f};
        ac[2] = (f32x4){0.f,0.f,0.f,0.f};
        ac[3] = (f32x4){0.f,0.f,0.f,0.f};
        #pragma unroll
        for (int ksh = 0; ksh < 32; ++ksh) {
          uint4 bv = acts4[L_HB_U4 + ksh * 64 + kq * 16 + (bq ^ (ksh & 7))];
          ac[ksh & 3] = __builtin_amdgcn_mfma_f32_16x16x32_f16(Ah[ksh], bc8(bv), ac[ksh & 3], 0, 0, 0);
        }
        f32x4 t = (ac[0] + ac[1]) + (ac[2] + ac[3]);

        float gf = sigm(t[0] + bsf);
        float gi = sigm(t[1] + bsi);
        float gc = tanh_c(t[2] + bsc);
        float go = sigm(t[3] + bso);
        cstate = gf * cstate + gi * gc;
        float hv = go * tanh_c(cstate);

        uint32_t hu = (uint32_t)__builtin_bit_cast(unsigned short, (_Float16)hv);
        uint32_t pA  = hu | ((uint32_t)__shfl_down((int)hu, 16) << 16);
        uint32_t hiw = (uint32_t)__shfl_down((int)pA, 32);
        if (kq == 0) {
          ushort* hp = hb16 + (size_t)((it + 1) & 1) * BH
                     + (size_t)(b0 + bq) * HH + (u0 + mt * 4);
          cohere_st8(hp, pA, hiw);
        }
        if (it == TT - 1) {
          out[(size_t)BTO + (size_t)(b0 + bq) * HH + unit] = hv;
          out[(size_t)BTO + BH + (size_t)(b0 + bq) * HH + unit] = cstate;
        }
        // drain THIS wave's h stores, then publish this wave's flag at once
        asm volatile("s_waitcnt vmcnt(0)" ::: "memory");
        if (lane == 0) cohere_st4(&flags[s * 4 + mt], (uint32_t)(it + 1));
      }
    } else {
      // ---- AUX: y-MFMA for y_{it-1} over h_{it-1} (still in h-LDS) ----
      if (it > 0) {
        f32x4 yc = (f32x4){0.f,0.f,0.f,0.f};
        #pragma unroll
        for (int k = 0; k < 8; ++k) {
          int ksh = mt * 8 + k;
          uint4 bv = acts4[L_HB_U4 + ksh * 64 + kq * 16 + (bq ^ (ksh & 7))];
          yc = __builtin_amdgcn_mfma_f32_16x16x32_f16(Yw[k], bc8(bv), yc, 0, 0, 0);
        }
        float* yp = ypart + (mt * 64 + lane) * 5;
        yp[0] = yc[0]; yp[1] = yc[1]; yp[2] = yc[2]; yp[3] = yc[3];
      }
    }
    lds_barrier(bar, ++bphase, lane);        // S1: h-LDS reads done; ypart ready

    // ---- gate threads: y finalize ; aux threads: x write ----
    if (tid < 128 && it > 0) {
      int fb = tid & 15, rr = tid >> 4;
      int l = (rr >> 2) * 16 + fb;
      float yv = ybias;
      #pragma unroll
      for (int w = 0; w < 4; ++w) yv += ypart[(w * 64 + l) * 5 + (rr & 3)];
      out[(size_t)(b0 + fb) * (TT * OO) + (size_t)(it - 1) * OO + s * 8 + rr] = yv;
    }
    if (!isGate && xok) {
      const float* xs = x + ((size_t)(b0 + sb) * TT + (it + 1)) * II + sj * 32;
      float4 xr[8];
      #pragma unroll
      for (int v = 0; v < 8; ++v) xr[v] = ((const float4*)xs)[v];
      #pragma unroll
      for (int v = 0; v < 4; ++v)
        acts4[sj * 64 + v * 16 + (sb ^ (sj & 7))] =
            make_uint4(pk_u32(xr[2*v].x, xr[2*v].y), pk_u32(xr[2*v].z, xr[2*v].w),
                       pk_u32(xr[2*v+1].x, xr[2*v+1].y), pk_u32(xr[2*v+1].z, xr[2*v+1].w));
    }
    lds_barrier(bar, ++bphase, lane);        // S2: x-LDS ready

    // ---- aux: xpart(it+1) ----
    if (!isGate && xok) {
      f32x4 ac[4];
      #pragma unroll
      for (int j = 0; j < 4; ++j) ac[j] = (f32x4){0.f,0.f,0.f,0.f};
      #pragma unroll
      for (int ks = 0; ks < 16; ++ks) {
        uint4 bv = acts4[ks * 64 + kq * 16 + (bq ^ (ks & 7))];
        ac[ks & 3] = __builtin_amdgcn_mfma_f32_16x16x32_f16(Ax[ks], bc8(bv), ac[ks & 3], 0, 0, 0);
      }
      f32x4 t = (ac[0] + ac[1]) + (ac[2] + ac[3]);
      float* xp = xpart + (mt * 64 + lane) * 4;
      xp[0] = t[0]; xp[1] = t[1]; xp[2] = t[2]; xp[3] = t[3];
    }

    if (it < TT) {
      // ---- DATAFLOW WAIT: poll own 2 producers' 8 wave-flags (4x8B) ----
      {
        const uint32_t tgt = (uint32_t)(it + 1);
        const uint32_t* fp = &flags[gj * 8];
        for (;;) {
          uint2 f0 = cohere_ld8(fp + 0);
          uint2 f1 = cohere_ld8(fp + 2);
          uint2 f2 = cohere_ld8(fp + 4);
          uint2 f3 = cohere_ld8(fp + 6);
          burn16();                          // overlap the load round-trip
          if (f0.x >= tgt && f0.y >= tgt && f1.x >= tgt && f1.y >= tgt &&
              f2.x >= tgt && f2.y >= tgt && f3.x >= tgt && f3.y >= tgt) break;
        }
        const ushort* hs = hb16 + (size_t)((it + 1) & 1) * BH
                         + (size_t)(b0 + gb) * HH + gj * 32;
        uint2 q[8];
        #pragma unroll
        for (int m = 0; m < 8; ++m) q[m] = cohere_ld8(hs + m * 4);
        #pragma unroll
        for (int sub = 0; sub < 4; ++sub)
          acts4[L_HB_U4 + gj * 64 + sub * 16 + (gb ^ (gj & 7))] =
              make_uint4(q[2*sub].x, q[2*sub].y, q[2*sub+1].x, q[2*sub+1].y);
      }
      lds_barrier(bar, ++bphase, lane);      // S3: h + xpart ready for it+1
    }
  }
}

extern "C" void kernel_launch(void* const* d_in, const int* in_sizes, int n_in,
                              void* d_out, int out_size, void* d_ws, size_t ws_size,
                              hipStream_t stream) {
  (void)in_sizes; (void)n_in; (void)out_size; (void)ws_size;
  const float* x   = (const float*)d_in[0];
  const float* Wf  = (const float*)d_in[1];
  const float* bf  = (const float*)d_in[2];
  const float* Wi  = (const float*)d_in[3];
  const float* bi  = (const float*)d_in[4];
  const float* Wc  = (const float*)d_in[5];
  const float* bc  = (const float*)d_in[6];
  const float* Wo  = (const float*)d_in[7];
  const float* bo  = (const float*)d_in[8];
  const float* Wfc = (const float*)d_in[9];
  const float* bfc = (const float*)d_in[10];
  float* out = (float*)d_out;
  float* ws  = (float*)d_ws;

  // zero flag words each call (replay-safe); h slots written before any read
  (void)hipMemsetAsync(d_ws, 0, (size_t)WS_HBUF * sizeof(float), stream);

  // pack fp16 MFMA fragment slabs
  const int nprep = 64 * 4 * 48 * 64 + 64 * 32 * 64;
  prep<<<dim3((nprep + 255) / 256), dim3(256), 0, stream>>>(Wf, Wi, Wc, Wo, Wfc, ws);

  // plain launch; 256 blocks <= 256 CUs => all co-resident for the spin protocol
  lstm_kernel<<<dim3(NBLK), dim3(NTHR), L_BYTES, stream>>>(
      x, bf, bi, bc, bo, bfc, out, ws);
}

// Round 21
// 3332.502 us; speedup vs baseline: 1.8836x; 1.0538x over previous
//
#include <hip/hip_runtime.h>
#include <stdint.h>

#define BB 64
#define TT 512
#define II 512
#define HH 1024
#define OO 512
#define NBLK 256
#define NTHR 512
#define NB 16            // batches per group
#define US 16            // units per slice

// ws float-offsets
#define WS_HBUF  1280                      // 2 slots x 64x1024 fp16 = 65536 floats
#define WS_ASLAB 66816                     // 64s x 4mt x 48ks x 64ln uint4
#define WS_YSLAB 3212544                   // 64s x 32ks x 64ln uint4
#define BTO (BB*TT*OO)
#define BH  (BB*HH)

// LDS: x-acts [64 koct][16] uint4 (16KB) | h-acts (32KB) | ypart [4][64][5] f32
//      | xpart [4][64][4] f32
#define L_HB_U4 1024                       // uint4 index of h region
#define L_YP_F  12288                      // float index of ypart
#define L_XP_F  (12288 + 1280)             // 13568
#define L_BYTES ((13568 + 1024) * 4)       // 58368

typedef __fp16 v8hf __attribute__((ext_vector_type(8)));   // MFMA operand type
typedef float f32x4 __attribute__((ext_vector_type(4)));
typedef _Float16 h2 __attribute__((ext_vector_type(2)));

static __device__ __forceinline__ v8hf bc8(uint4 v) { return __builtin_bit_cast(v8hf, v); }
static __device__ __forceinline__ uint32_t pk_u32(float a, float b) {
  return __builtin_bit_cast(uint32_t, __builtin_amdgcn_cvt_pkrtz(a, b));
}

__device__ __forceinline__ float sigm(float v) { return 1.0f / (1.0f + __expf(-v)); }
__device__ __forceinline__ float tanh_c(float v) {
  v = fminf(fmaxf(v, -20.0f), 20.0f);
  float e = __expf(-2.0f * v);
  return (1.0f - e) / (1.0f + e);
}

// agent-scope (sc0 sc1): per-access coherence, NO cache-wide ops, NO atomics
__device__ __forceinline__ uint2 cohere_ld8(const void* p) {
  unsigned long long q = __hip_atomic_load((const unsigned long long*)p,
                                           __ATOMIC_RELAXED, __HIP_MEMORY_SCOPE_AGENT);
  return __builtin_bit_cast(uint2, q);
}
__device__ __forceinline__ void cohere_st8(void* p, uint32_t lo, uint32_t hi) {
  uint2 v = make_uint2(lo, hi);
  __hip_atomic_store((unsigned long long*)p, __builtin_bit_cast(unsigned long long, v),
                     __ATOMIC_RELAXED, __HIP_MEMORY_SCOPE_AGENT);
}
__device__ __forceinline__ void cohere_st4(void* p, uint32_t v) {
  __hip_atomic_store((uint32_t*)p, v, __ATOMIC_RELAXED, __HIP_MEMORY_SCOPE_AGENT);
}

// -------- prep: pack A-slab (gate weights, MFMA A-frag order) + y-slab --------
__global__ void __launch_bounds__(256) prep(
    const float* __restrict__ Wf, const float* __restrict__ Wi,
    const float* __restrict__ Wc, const float* __restrict__ Wo,
    const float* __restrict__ Wfc, float* __restrict__ ws)
{
  const int NA = 64 * 4 * 48 * 64;
  const int NY = 64 * 32 * 64;
  int idx = blockIdx.x * 256 + threadIdx.x;
  if (idx < NA) {
    int s = idx / (4 * 48 * 64);
    int rem = idx % (4 * 48 * 64);
    int mt = rem / (48 * 64);
    int rem2 = rem % (48 * 64);
    int ks = rem2 >> 6, ln = rem2 & 63;
    int r = ln & 15, kq = ln >> 4;
    int unit = s * 16 + mt * 4 + (r >> 2), gate = r & 3;
    const float* W = (gate == 0) ? Wf : (gate == 1) ? Wi : (gate == 2) ? Wc : Wo;
    const float* src = W + (size_t)unit * 1536 + ks * 32 + kq * 8;
    uint32_t p[4];
    #pragma unroll
    for (int j = 0; j < 4; ++j) {
      h2 t; t.x = (_Float16)src[2*j]; t.y = (_Float16)src[2*j+1];   // RNE
      p[j] = __builtin_bit_cast(uint32_t, t);
    }
    ((uint4*)(ws + WS_ASLAB))[idx] = make_uint4(p[0], p[1], p[2], p[3]);
  } else if (idx < NA + NY) {
    int j2 = idx - NA;
    int s = j2 / (32 * 64);
    int rem = j2 % (32 * 64);
    int ks = rem >> 6, ln = rem & 63;
    int r = ln & 15, kq = ln >> 4;
    uint4 outv = make_uint4(0, 0, 0, 0);
    if (r < 8) {
      const float* src = Wfc + (size_t)(s * 8 + r) * 1024 + ks * 32 + kq * 8;
      uint32_t p[4];
      #pragma unroll
      for (int j = 0; j < 4; ++j) {
        h2 t; t.x = (_Float16)src[2*j]; t.y = (_Float16)src[2*j+1];
        p[j] = __builtin_bit_cast(uint32_t, t);
      }
      outv = make_uint4(p[0], p[1], p[2], p[3]);
    }
    ((uint4*)(ws + WS_YSLAB))[j2] = outv;
  }
}

__global__ void __launch_bounds__(NTHR, 2)
lstm_kernel(const float* __restrict__ x,
            const float* __restrict__ bf, const float* __restrict__ bi,
            const float* __restrict__ bc, const float* __restrict__ bo,
            const float* __restrict__ bfc,
            float* __restrict__ out, float* __restrict__ ws)
{
  extern __shared__ float ldsf[];
  uint4* acts4 = (uint4*)ldsf;               // x: [0,1024) ; h: [1024,3072)
  float* ypart = ldsf + L_YP_F;              // [4][64][5]
  float* xpart = ldsf + L_XP_F;              // [4][64][4]

  const int tid  = threadIdx.x;
  const int blk  = blockIdx.x;
  const int wave = tid >> 6;
  const int lane = tid & 63;
  const bool isGate = (wave < 4);
  const int mt = wave & 3;                   // m-tile for this wave's role
  const int g = blk >> 6, s = blk & 63;
  const int b0 = g * NB;
  const int u0 = s * US;

  uint32_t* ctrl  = (uint32_t*)ws;
  uint32_t* flags = ctrl + g * 128;          // flags[s] = it+1, one word per block
  ushort* hb16 = (ushort*)(ws + WS_HBUF);

  const int bq = lane & 15, kq = lane >> 4;  // MFMA B-col/batch ; k-group & row-quad
  const int tid2 = tid & 255;                // aux staging index
  const int sb = tid2 >> 4, sj = tid2 & 15;  // x staging: batch, row/16
  const int gb = tid >> 5, gj = tid & 31;    // gather: batch, row/32 (512 thr)

  // ---- persistent fragments (role-split to fit 2 waves/SIMD) ----
  v8hf Ah[32];                               // gate: h-part A-frags (128 VGPR)
  v8hf Ax[16];                               // aux: x-part A-frags  (64 VGPR)
  v8hf Yw[8];                                // aux: Wfc k-slice     (32 VGPR)
  if (isGate) {
    const uint4* wpA = (const uint4*)(ws + WS_ASLAB)
                     + ((size_t)(s * 4 + mt) * 48 + 16) * 64 + lane;
    #pragma unroll
    for (int k = 0; k < 32; ++k) Ah[k] = bc8(wpA[k * 64]);
  } else {
    const uint4* wpA = (const uint4*)(ws + WS_ASLAB)
                     + ((size_t)(s * 4 + mt) * 48) * 64 + lane;
    #pragma unroll
    for (int k = 0; k < 16; ++k) Ax[k] = bc8(wpA[k * 64]);
    const uint4* wpY = (const uint4*)(ws + WS_YSLAB)
                     + ((size_t)(s * 32 + mt * 8)) * 64 + lane;
    #pragma unroll
    for (int k = 0; k < 8; ++k) Yw[k] = bc8(wpY[k * 64]);
  }
  const int unit = u0 + mt * 4 + kq;         // gate waves: owned unit
  const float bsf = isGate ? bf[unit] : 0.f;
  const float bsi = isGate ? bi[unit] : 0.f;
  const float bsc = isGate ? bc[unit] : 0.f;
  const float bso = isGate ? bo[unit] : 0.f;
  const float ybias = (tid < 128) ? bfc[s * 8 + (tid >> 4)] : 0.0f;
  float cstate = 0.0f;

  // ---- prologue ----
  if (!isGate) {                             // aux: stage x_0
    const float* xs = x + ((size_t)(b0 + sb) * TT + 0) * II + sj * 32;
    #pragma unroll
    for (int v = 0; v < 4; ++v) {
      float4 u = ((const float4*)xs)[2*v], w = ((const float4*)xs)[2*v+1];
      acts4[sj * 64 + v * 16 + (sb ^ (sj & 7))] =
          make_uint4(pk_u32(u.x,u.y), pk_u32(u.z,u.w), pk_u32(w.x,w.y), pk_u32(w.z,w.w));
    }
  } else {                                   // gate: zero h-LDS (h_{-1}=0)
    #pragma unroll
    for (int j = 0; j < 8; ++j)
      acts4[L_HB_U4 + tid2 * 8 + j] = make_uint4(0,0,0,0);
  }
  __syncthreads();
  if (!isGate) {                             // aux: xpart(0)
    f32x4 ac[4];
    #pragma unroll
    for (int j = 0; j < 4; ++j) ac[j] = (f32x4){0.f,0.f,0.f,0.f};
    #pragma unroll
    for (int ks = 0; ks < 16; ++ks) {
      uint4 bv = acts4[ks * 64 + kq * 16 + (bq ^ (ks & 7))];
      ac[ks & 3] = __builtin_amdgcn_mfma_f32_16x16x32_f16(Ax[ks], bc8(bv), ac[ks & 3], 0, 0, 0);
    }
    f32x4 t = (ac[0] + ac[1]) + (ac[2] + ac[3]);
    float* xp = xpart + (mt * 64 + lane) * 4;
    xp[0] = t[0]; xp[1] = t[1]; xp[2] = t[2]; xp[3] = t[3];
  }
  __syncthreads();

  for (int it = 0; it <= TT; ++it) {
    const bool xok = (it + 1 < TT);

    if (isGate) {
      // ---- GATE: C-init from xpart, 32 h-MFMA, state, h-store ----
      if (it < TT) {
        const float* xp = xpart + (mt * 64 + lane) * 4;
        f32x4 ac[4];
        ac[0] = (f32x4){xp[0], xp[1], xp[2], xp[3]};
        ac[1] = (f32x4){0.f,0.f,0.f,0.f};
        ac[2] = (f32x4){0.f,0.f,0.f,0.f};
        ac[3] = (f32x4){0.f,0.f,0.f,0.f};
        #pragma unroll
        for (int ksh = 0; ksh < 32; ++ksh) {
          uint4 bv = acts4[L_HB_U4 + ksh * 64 + kq * 16 + (bq ^ (ksh & 7))];
          ac[ksh & 3] = __builtin_amdgcn_mfma_f32_16x16x32_f16(Ah[ksh], bc8(bv), ac[ksh & 3], 0, 0, 0);
        }
        f32x4 t = (ac[0] + ac[1]) + (ac[2] + ac[3]);

        float gf = sigm(t[0] + bsf);
        float gi = sigm(t[1] + bsi);
        float gc = tanh_c(t[2] + bsc);
        float go = sigm(t[3] + bso);
        cstate = gf * cstate + gi * gc;
        float hv = go * tanh_c(cstate);

        uint32_t hu = (uint32_t)__builtin_bit_cast(unsigned short, (_Float16)hv);
        uint32_t pA  = hu | ((uint32_t)__shfl_down((int)hu, 16) << 16);
        uint32_t hiw = (uint32_t)__shfl_down((int)pA, 32);
        if (kq == 0) {
          ushort* hp = hb16 + (size_t)((it + 1) & 1) * BH
                     + (size_t)(b0 + bq) * HH + (u0 + mt * 4);
          cohere_st8(hp, pA, hiw);
        }
        if (it == TT - 1) {
          out[(size_t)BTO + (size_t)(b0 + bq) * HH + unit] = hv;
          out[(size_t)BTO + BH + (size_t)(b0 + bq) * HH + unit] = cstate;
        }
        asm volatile("s_waitcnt vmcnt(0)" ::: "memory");   // this wave's h drained
      }
    } else {
      // ---- AUX: y-MFMA for y_{it-1} over h_{it-1} (still in h-LDS) ----
      if (it > 0) {
        f32x4 yc = (f32x4){0.f,0.f,0.f,0.f};
        #pragma unroll
        for (int k = 0; k < 8; ++k) {
          int ksh = mt * 8 + k;
          uint4 bv = acts4[L_HB_U4 + ksh * 64 + kq * 16 + (bq ^ (ksh & 7))];
          yc = __builtin_amdgcn_mfma_f32_16x16x32_f16(Yw[k], bc8(bv), yc, 0, 0, 0);
        }
        float* yp = ypart + (mt * 64 + lane) * 5;
        yp[0] = yc[0]; yp[1] = yc[1]; yp[2] = yc[2]; yp[3] = yc[3];
      }
    }
    __syncthreads();                         // S1: h drained (gate waves), reads done

    // ---- PUBLISH: plain sc1 flag store, no atomic, no contention ----
    if (it < TT && tid == 0)
      cohere_st4(&flags[s], (uint32_t)(it + 1));

    // ---- gate threads: y finalize ; aux threads: x write ----
    if (tid < 128 && it > 0) {
      int fb = tid & 15, rr = tid >> 4;
      int l = (rr >> 2) * 16 + fb;
      float yv = ybias;
      #pragma unroll
      for (int w = 0; w < 4; ++w) yv += ypart[(w * 64 + l) * 5 + (rr & 3)];
      out[(size_t)(b0 + fb) * (TT * OO) + (size_t)(it - 1) * OO + s * 8 + rr] = yv;
    }
    if (!isGate && xok) {
      const float* xs = x + ((size_t)(b0 + sb) * TT + (it + 1)) * II + sj * 32;
      float4 xr[8];
      #pragma unroll
      for (int v = 0; v < 8; ++v) xr[v] = ((const float4*)xs)[v];
      #pragma unroll
      for (int v = 0; v < 4; ++v)
        acts4[sj * 64 + v * 16 + (sb ^ (sj & 7))] =
            make_uint4(pk_u32(xr[2*v].x, xr[2*v].y), pk_u32(xr[2*v].z, xr[2*v].w),
                       pk_u32(xr[2*v+1].x, xr[2*v+1].y), pk_u32(xr[2*v+1].z, xr[2*v+1].w));
    }
    __syncthreads();                         // S2: x-LDS ready

    // ---- aux: xpart(it+1) ----
    if (!isGate && xok) {
      f32x4 ac[4];
      #pragma unroll
      for (int j = 0; j < 4; ++j) ac[j] = (f32x4){0.f,0.f,0.f,0.f};
      #pragma unroll
      for (int ks = 0; ks < 16; ++ks) {
        uint4 bv = acts4[ks * 64 + kq * 16 + (bq ^ (ks & 7))];
        ac[ks & 3] = __builtin_amdgcn_mfma_f32_16x16x32_f16(Ax[ks], bc8(bv), ac[ks & 3], 0, 0, 0);
      }
      f32x4 t = (ac[0] + ac[1]) + (ac[2] + ac[3]);
      float* xp = xpart + (mt * 64 + lane) * 4;
      xp[0] = t[0]; xp[1] = t[1]; xp[2] = t[2]; xp[3] = t[3];
    }

    if (it < TT) {
      // ---- DATAFLOW WAIT+GATHER: each thread waits only for ITS 2 producers ----
      {
        const uint32_t tgt = (uint32_t)(it + 1);
        for (;;) {
          uint2 f = cohere_ld8(&flags[gj * 2]);
          if (f.x >= tgt && f.y >= tgt) break;
          __builtin_amdgcn_s_sleep(1);
        }
        const ushort* hs = hb16 + (size_t)((it + 1) & 1) * BH
                         + (size_t)(b0 + gb) * HH + gj * 32;
        uint2 q[8];
        #pragma unroll
        for (int m = 0; m < 8; ++m) q[m] = cohere_ld8(hs + m * 4);
        #pragma unroll
        for (int sub = 0; sub < 4; ++sub)
          acts4[L_HB_U4 + gj * 64 + sub * 16 + (gb ^ (gj & 7))] =
              make_uint4(q[2*sub].x, q[2*sub].y, q[2*sub+1].x, q[2*sub+1].y);
      }
      __syncthreads();                       // S3: h + xpart ready for it+1
    }
  }
}

extern "C" void kernel_launch(void* const* d_in, const int* in_sizes, int n_in,
                              void* d_out, int out_size, void* d_ws, size_t ws_size,
                              hipStream_t stream) {
  (void)in_sizes; (void)n_in; (void)out_size; (void)ws_size;
  const float* x   = (const float*)d_in[0];
  const float* Wf  = (const float*)d_in[1];
  const float* bf  = (const float*)d_in[2];
  const float* Wi  = (const float*)d_in[3];
  const float* bi  = (const float*)d_in[4];
  const float* Wc  = (const float*)d_in[5];
  const float* bc  = (const float*)d_in[6];
  const float* Wo  = (const float*)d_in[7];
  const float* bo  = (const float*)d_in[8];
  const float* Wfc = (const float*)d_in[9];
  const float* bfc = (const float*)d_in[10];
  float* out = (float*)d_out;
  float* ws  = (float*)d_ws;

  // zero flag words each call (replay-safe); h slots written before any read
  (void)hipMemsetAsync(d_ws, 0, (size_t)WS_HBUF * sizeof(float), stream);

  // pack fp16 MFMA fragment slabs
  const int nprep = 64 * 4 * 48 * 64 + 64 * 32 * 64;
  prep<<<dim3((nprep + 255) / 256), dim3(256), 0, stream>>>(Wf, Wi, Wc, Wo, Wfc, ws);

  // plain launch; 256 blocks <= 256 CUs => all co-resident for the spin protocol
  lstm_kernel<<<dim3(NBLK), dim3(NTHR), L_BYTES, stream>>>(
      x, bf, bi, bc, bo, bfc, out, ws);
}